// Round 15
// baseline (163.641 us; speedup 1.0000x reference)
//
#include <hip/hip_runtime.h>
#include <hip/hip_bf16.h>

#define BB 64
#define SS 512
#define TT 32
#define ENDI 31
#define NSEG 32
#define SEGLEN 16
#define HALF 8
#define ACCS 0                    // float accumulator for sum_b loss_b
#define CNTS 1                    // uint: comb completion counter
#define BCNT 2                    // uint[64]: per-batch seg-arrival counters
#define GOLDB 128                 // gold partials, BB*NSEG floats
#define MATB (GOLDB + BB * NSEG)  // matrices, BB*NSEG*1056 floats

typedef __attribute__((ext_vector_type(8))) short s8v;    // 8 bf16 (4 VGPR)
typedef __attribute__((ext_vector_type(16))) float fx16;  // MFMA accumulator

union S8U {
  s8v v;
  unsigned int u[4];
};

__device__ __forceinline__ unsigned int cvtpk_bf16(float a, float b) {
  unsigned int r;
  asm("v_cvt_pk_bf16_f32 %0, %1, %2" : "=v"(r) : "v"(a), "v"(b));
  return r;
}

// ---------------------------------------------------------------------------
// Single fused kernel. One BLOCK (2 waves) per (batch, segment) task with a
// 2D-swizzled task map (seg = blk>>6, b = (blk+seg)&63) so each CU's 8
// co-resident blocks mix batches AND segments -> per-CU read bytes balanced.
// Stage 1 (R13-proven): wave0 P_lo = E7..E0, wave1 P_hi = E15..E8, merge via
// LDS + 1 matmul -> normalized 32x32 f32 matrix + esum.
// Stage 2 (fused comb): per-batch arrival counter; the 32nd-arriving block
// of batch b runs the comb chain for b (release: per-thread __threadfence
// before counter; acquire: __threadfence after observing count).
__global__ __launch_bounds__(128) void crf_kernel(
    const float* __restrict__ sc, const int* __restrict__ targets,
    const int* __restrict__ lengths, float* __restrict__ ws,
    float* __restrict__ out) {
  const int blk = blockIdx.x;
  const int seg = blk >> 6;          // [0, 32)
  const int b = (blk + seg) & 63;    // swizzled batch (bijective per seg)
  const int tid = threadIdx.x;
  const int wv = tid >> 6;  // 0: low half-chain / fwd-dir, 1: high / bwd-dir
  const int l = tid & 63;
  const int c = l & 31;
  const int h = l >> 5;
  const int len = lengths[b];
  const int lo = seg * SEGLEN;

  __shared__ alignas(16) float lm[TT * 33];  // P_hi staging, +1 pad per row
  __shared__ float meta0;                    // esum1 from wave1
  __shared__ alignas(16) float stc[2][TT];   // comb state per direction
  __shared__ float esvS[2];
  __shared__ unsigned lastS;

  float* mout = ws + MATB + (size_t)(b * NSEG + seg) * 1056;

  // ---- gold partial for s in [lo, lo+SEGLEN), wave0 only ----
  if (wv == 0) {
    float gv = 0.f;
    if (l < SEGLEN) {
      int s = lo + l;
      if (s < len) {
        int idx = b * SS + s;
        gv = sc[(size_t)idx * 1024 + (size_t)targets[idx]];
      }
    }
#pragma unroll
    for (int o = 32; o; o >>= 1) gv += __shfl_xor(gv, o);
    if (l == 0) ws[GOLDB + b * NSEG + seg] = gv;
  }

#define LOADE(buf, T)                                                     \
  do {                                                                    \
    const float* _p = base + (size_t)(T) * 1024 + c * 32 + 8 * h;         \
    float4 _a = *(const float4*)_p;                                       \
    float4 _b = *(const float4*)(_p + 4);                                 \
    float4 _c = *(const float4*)(_p + 16);                                \
    float4 _d = *(const float4*)(_p + 20);                                \
    buf[0] = _a.x;  buf[1] = _a.y;  buf[2] = _a.z;  buf[3] = _a.w;        \
    buf[4] = _b.x;  buf[5] = _b.y;  buf[6] = _b.z;  buf[7] = _b.w;        \
    buf[8] = _c.x;  buf[9] = _c.y;  buf[10] = _c.z; buf[11] = _c.w;       \
    buf[12] = _d.x; buf[13] = _d.y; buf[14] = _d.z; buf[15] = _d.w;       \
  } while (0)

#define RESCALE(SVAR)                                                     \
  do {                                                                    \
    float _mx = Cl[0];                                                    \
    _Pragma("unroll") for (int q = 1; q < 16; ++q) _mx = fmaxf(_mx, Cl[q]); \
    _mx = fmaxf(_mx, __shfl_xor(_mx, 32));                                \
    _mx = fmaxf(_mx, __shfl_xor(_mx, 1));                                 \
    _mx = fmaxf(_mx, __shfl_xor(_mx, 2));                                 \
    _mx = fmaxf(_mx, __shfl_xor(_mx, 4));                                 \
    _mx = fmaxf(_mx, __shfl_xor(_mx, 8));                                 \
    _mx = fmaxf(_mx, __shfl_xor(_mx, 16));                                \
    int _ex = ((__float_as_int(_mx) >> 23) & 255) - 127;                  \
    SVAR = __int_as_float((unsigned)(127 - _ex) << 23);                   \
    esum += _ex;                                                          \
  } while (0)

#define REPACK()                                                          \
  do {                                                                    \
    unsigned int W[8], X[8];                                              \
    _Pragma("unroll") for (int q = 0; q < 8; ++q) W[q] =                  \
        cvtpk_bf16(Cl[2 * q] * s, Cl[2 * q + 1] * s);                     \
    _Pragma("unroll") for (int q = 0; q < 8; ++q) X[q] =                  \
        __shfl_xor((int)W[q], 32);                                        \
    B0.u[0] = h ? X[2] : W[0];                                            \
    B0.u[1] = h ? X[3] : W[1];                                            \
    B0.u[2] = h ? W[2] : X[0];                                            \
    B0.u[3] = h ? W[3] : X[1];                                            \
    B1.u[0] = h ? X[6] : W[4];                                            \
    B1.u[1] = h ? X[7] : W[5];                                            \
    B1.u[2] = h ? W[6] : X[4];                                            \
    B1.u[3] = h ? W[7] : X[5];                                            \
  } while (0)

  if (len <= lo) {  // whole segment past the sequence: identity matrix
    if (wv == 0) {
#pragma unroll
      for (int r = 0; r < 16; ++r) {
        int row = (r & 3) + 8 * (r >> 2) + 4 * h;
        mout[row * 32 + c] = (row == c) ? 1.0f : 0.0f;
      }
      if (l == 0) mout[1024] = 0.0f;
    }
  } else {
    const int rel = len - lo;  // > 0
    // wave0 covers steps [0,8), wave1 covers [8,16)
    const int nst =
        (wv == 0)
            ? (rel < HALF ? rel : HALF)
            : (rel - HALF < 0 ? 0 : (rel - HALF < HALF ? rel - HALF : HALF));
    const float* base = sc + ((size_t)b * SS + lo + wv * HALF) * 1024;

    // B state = identity (bf16 1.0 = 0x3F80 at m == c)
    S8U B0, B1;
#pragma unroll
    for (int q = 0; q < 4; ++q) {
      B0.u[q] = 0u;
      B1.u[q] = 0u;
    }
    {
      int j0 = c - 8 * h;
      if (j0 >= 0 && j0 < 8) B0.u[j0 >> 1] |= 0x3F80u << (16 * (j0 & 1));
      int j1 = c - 16 - 8 * h;
      if (j1 >= 0 && j1 < 8) B1.u[j1 >> 1] |= 0x3F80u << (16 * (j1 & 1));
    }

    int esum = 0;
    fx16 C;
#pragma unroll
    for (int q = 0; q < 16; ++q) C[q] = 0.f;

    if (nst == HALF) {
      // ---- full 8-step half-chain: 4 phases x 2 steps, L depth 2 ----
      float L[2][16];
      S8U A2[2][2];
      LOADE(L[0], 0);
      LOADE(L[1], 1);
#pragma unroll
      for (int ph = 0; ph < 4; ++ph) {
#pragma unroll
        for (int k = 0; k < 2; ++k) {
#pragma unroll
          for (int q = 0; q < 4; ++q) {
            A2[k][0].u[q] =
                cvtpk_bf16(__expf(L[k][2 * q]), __expf(L[k][2 * q + 1]));
            A2[k][1].u[q] =
                cvtpk_bf16(__expf(L[k][8 + 2 * q]), __expf(L[k][9 + 2 * q]));
          }
        }
        if (ph < 3) {
          LOADE(L[0], ph * 2 + 2);
          LOADE(L[1], ph * 2 + 3);
        }
#pragma unroll
        for (int k = 0; k < 2; ++k) {
          const int t = ph * 2 + k;
          fx16 Cl;
#pragma unroll
          for (int q = 0; q < 16; ++q) Cl[q] = 0.f;
          Cl = __builtin_amdgcn_mfma_f32_32x32x16_bf16(A2[k][0].v, B0.v, Cl,
                                                       0, 0, 0);
          Cl = __builtin_amdgcn_mfma_f32_32x32x16_bf16(A2[k][1].v, B1.v, Cl,
                                                       0, 0, 0);
          if (t == HALF - 1) {
            C = Cl;
          } else {
            float s = 1.0f;
            if (t == 3) RESCALE(s);
            REPACK();
          }
        }
      }
    } else if (nst > 0) {
      // ---- partial half-chain: R6-proven serial loop ----
      float r0[16], r1[16], r2[16];
      LOADE(r0, 0);
      LOADE(r1, (nst > 1) ? 1 : 0);
      LOADE(r2, (nst > 2) ? 2 : 0);

#define STEPB(RB)                                                            \
      do {                                                                  \
        S8U A0, A1;                                                         \
        _Pragma("unroll") for (int q = 0; q < 4; ++q) {                     \
          A0.u[q] = cvtpk_bf16(__expf(RB[2 * q]), __expf(RB[2 * q + 1]));   \
          A1.u[q] = cvtpk_bf16(__expf(RB[8 + 2 * q]), __expf(RB[9 + 2 * q]));\
        }                                                                   \
        int _pf = t + 3;                                                    \
        if (_pf >= nst) _pf = nst - 1;                                      \
        LOADE(RB, _pf);                                                     \
        fx16 Cl;                                                            \
        _Pragma("unroll") for (int q = 0; q < 16; ++q) Cl[q] = 0.f;         \
        Cl = __builtin_amdgcn_mfma_f32_32x32x16_bf16(A0.v, B0.v, Cl, 0, 0, 0);\
        Cl = __builtin_amdgcn_mfma_f32_32x32x16_bf16(A1.v, B1.v, Cl, 0, 0, 0);\
        if (t + 1 < nst) {                                                  \
          float s = 1.0f;                                                   \
          if ((t & 3) == 3) RESCALE(s);                                     \
          REPACK();                                                         \
        } else {                                                            \
          C = Cl;                                                           \
        }                                                                   \
      } while (0)

      int t = 0;
      while (t < nst) {
        STEPB(r0);
        ++t;
        if (t >= nst) break;
        STEPB(r1);
        ++t;
        if (t >= nst) break;
        STEPB(r2);
        ++t;
      }
#undef STEPB
    }

    // ---- wave1: normalize its product and stage to LDS ----
    if (wv == 1 && nst > 0) {
      float mx = C[0];
#pragma unroll
      for (int q = 1; q < 16; ++q) mx = fmaxf(mx, C[q]);
      mx = fmaxf(mx, __shfl_xor(mx, 32));
      mx = fmaxf(mx, __shfl_xor(mx, 1));
      mx = fmaxf(mx, __shfl_xor(mx, 2));
      mx = fmaxf(mx, __shfl_xor(mx, 4));
      mx = fmaxf(mx, __shfl_xor(mx, 8));
      mx = fmaxf(mx, __shfl_xor(mx, 16));
      int ex = ((__float_as_int(mx) >> 23) & 255) - 127;
      float s1 = __int_as_float((unsigned)(127 - ex) << 23);
      esum += ex;
#pragma unroll
      for (int r = 0; r < 16; ++r) {
        int row = (r & 3) + 8 * (r >> 2) + 4 * h;
        lm[row * 33 + c] = C[r] * s1;
      }
      if (l == 0) meta0 = (float)esum;
    }
    __syncthreads();

    if (wv == 0) {
      if (rel > HALF) {
        {
          fx16 Cl = C;
          float s = 1.0f;
          RESCALE(s);
          REPACK();
        }
        S8U Am0, Am1;
#pragma unroll
        for (int q = 0; q < 4; ++q) {
          Am0.u[q] = cvtpk_bf16(lm[c * 33 + 8 * h + 2 * q],
                                lm[c * 33 + 8 * h + 2 * q + 1]);
          Am1.u[q] = cvtpk_bf16(lm[c * 33 + 16 + 8 * h + 2 * q],
                                lm[c * 33 + 16 + 8 * h + 2 * q + 1]);
        }
        fx16 Cm;
#pragma unroll
        for (int q = 0; q < 16; ++q) Cm[q] = 0.f;
        Cm = __builtin_amdgcn_mfma_f32_32x32x16_bf16(Am0.v, B0.v, Cm, 0, 0, 0);
        Cm = __builtin_amdgcn_mfma_f32_32x32x16_bf16(Am1.v, B1.v, Cm, 0, 0, 0);
        C = Cm;
        esum += (int)meta0;
      }
      float mx = C[0];
#pragma unroll
      for (int q = 1; q < 16; ++q) mx = fmaxf(mx, C[q]);
      mx = fmaxf(mx, __shfl_xor(mx, 32));
      mx = fmaxf(mx, __shfl_xor(mx, 1));
      mx = fmaxf(mx, __shfl_xor(mx, 2));
      mx = fmaxf(mx, __shfl_xor(mx, 4));
      mx = fmaxf(mx, __shfl_xor(mx, 8));
      mx = fmaxf(mx, __shfl_xor(mx, 16));
      int ex = ((__float_as_int(mx) >> 23) & 255) - 127;
      float s = __int_as_float((unsigned)(127 - ex) << 23);
      esum += ex;
#pragma unroll
      for (int r = 0; r < 16; ++r) {
        int row = (r & 3) + 8 * (r >> 2) + 4 * h;
        mout[row * 32 + c] = C[r] * s;
      }
      if (l == 0) mout[1024] = (float)esum;
    }
  }
#undef REPACK
#undef RESCALE
#undef LOADE

  // ---- release own stores, count arrival; 32nd block runs comb for b ----
  __threadfence();  // per-thread release of this thread's matrix/gold stores
  __syncthreads();
  if (tid == 0) {
    unsigned old = atomicAdd((unsigned*)ws + BCNT + b, 1u);
    lastS = (old == NSEG - 1) ? 1u : 0u;
  }
  __syncthreads();
  if (!lastS) return;
  __threadfence();  // acquire: invalidate stale cache before matrix reads

  // ---- comb for batch b (R8-proven chain, 2 waves = 2 directions) ----
#define FENCE() asm volatile("s_waitcnt lgkmcnt(0)" ::: "memory")
#define LOADM(buf, SEG)                                                     \
  do {                                                                      \
    const float* _m = segbase + (size_t)(b * NSEG + (SEG)) * 1056;          \
    if (wv == 0) { /* need M[c][h16+j]: contiguous */                       \
      const float4* _p = (const float4*)(_m + c * 32 + h * 16);             \
      float4 _a = _p[0], _b2 = _p[1], _c2 = _p[2], _d = _p[3];              \
      buf[0] = _a.x;  buf[1] = _a.y;  buf[2] = _a.z;  buf[3] = _a.w;        \
      buf[4] = _b2.x; buf[5] = _b2.y; buf[6] = _b2.z; buf[7] = _b2.w;       \
      buf[8] = _c2.x; buf[9] = _c2.y; buf[10] = _c2.z; buf[11] = _c2.w;     \
      buf[12] = _d.x; buf[13] = _d.y; buf[14] = _d.z; buf[15] = _d.w;       \
    } else { /* need M[h16+j][c]: stride 32, coalesced across lanes */      \
      const float* _p = _m + (h * 16) * 32 + c;                             \
      _Pragma("unroll") for (int _j = 0; _j < 16; ++_j)                     \
          buf[_j] = _p[_j * 32];                                            \
    }                                                                       \
  } while (0)

  {
    const float* segbase = ws + MATB;
    const int half = NSEG >> 1;
    float cur = wv ? ((c == ENDI) ? 1.0f : 0.0f) : 1.0f;
    stc[wv][c] = cur;
    FENCE();
    float esv = 0.f;

    float mc[16], mn[16];
#pragma unroll
    for (int q = 0; q < 16; ++q) mn[q] = 0.f;
    {
      int seg0 = wv ? (NSEG - 1) : 0;
      LOADM(mc, seg0);
    }
    for (int k = 0; k < half; ++k) {
      int segn = wv ? (NSEG - 2 - k) : (k + 1);
      if (k + 1 < half) LOADM(mn, segn);
      int segc = wv ? (NSEG - 1 - k) : k;
      esv += segbase[(size_t)(b * NSEG + segc) * 1056 + 1024];
      const float4* g4 = (const float4*)stc[wv];
      float4 g0 = g4[h * 4 + 0], g1 = g4[h * 4 + 1], g2 = g4[h * 4 + 2],
             g3 = g4[h * 4 + 3];
      float g[16] = {g0.x, g0.y, g0.z, g0.w, g1.x, g1.y, g1.z, g1.w,
                     g2.x, g2.y, g2.z, g2.w, g3.x, g3.y, g3.z, g3.w};
      float acc[4];
#pragma unroll
      for (int q = 0; q < 4; ++q) {
        acc[q] = mc[4 * q] * g[4 * q];
#pragma unroll
        for (int t = 1; t < 4; ++t)
          acc[q] = fmaf(mc[4 * q + t], g[4 * q + t], acc[q]);
      }
      float part = (acc[0] + acc[1]) + (acc[2] + acc[3]);
      cur = part + __shfl_xor(part, 32);
      if ((k & 3) == 3) {  // power-of-2 rescale (growth <= 2^24 between)
        float mxv = cur;
        mxv = fmaxf(mxv, __shfl_xor(mxv, 1));
        mxv = fmaxf(mxv, __shfl_xor(mxv, 2));
        mxv = fmaxf(mxv, __shfl_xor(mxv, 4));
        mxv = fmaxf(mxv, __shfl_xor(mxv, 8));
        mxv = fmaxf(mxv, __shfl_xor(mxv, 16));
        int exv = ((__float_as_int(mxv) >> 23) & 255) - 127;
        cur *= __int_as_float((unsigned)(127 - exv) << 23);
        esv += (float)exv;
      }
      FENCE();
      stc[wv][c] = cur;
      FENCE();
#pragma unroll
      for (int q = 0; q < 16; ++q) mc[q] = mn[q];
    }

    if (l == 0) esvS[wv] = esv;
    __syncthreads();

    if (wv == 0) {
      float pr = stc[0][c] * stc[1][c];
      float gd = ws[GOLDB + b * NSEG + c];
#pragma unroll
      for (int o = 16; o; o >>= 1) {
        pr += __shfl_xor(pr, o);
        gd += __shfl_xor(gd, o);
      }
      if (l == 0) {
        float loss =
            (esvS[0] + esvS[1]) * 0.6931471805599453f + __logf(pr) - gd;
        atomicAdd(&ws[ACCS], loss);
        __threadfence();
        unsigned old = atomicAdd(&((unsigned*)ws)[CNTS], 1u);
        if (old == BB - 1) {  // last batch: publish
          float v = atomicAdd(&ws[ACCS], 0.0f);
          out[0] = v;
        }
      }
    }
  }
#undef LOADM
#undef FENCE
}

// ---------------------------------------------------------------------------
extern "C" void kernel_launch(void* const* d_in, const int* in_sizes, int n_in,
                              void* d_out, int out_size, void* d_ws,
                              size_t ws_size, hipStream_t stream) {
  const float* scores = (const float*)d_in[0];
  const int* targets = (const int*)d_in[1];
  const int* lengths = (const int*)d_in[2];
  float* out = (float*)d_out;
  float* ws = (float*)d_ws;

  // zero ACCS/CNTS/per-batch arrival counters (floats [0,128) = 512 B)
  hipMemsetAsync(d_ws, 0, 512, stream);
  crf_kernel<<<BB * NSEG, 128, 0, stream>>>(scores, targets, lengths, ws,
                                            out);
}

// Round 16
// 45.416 us; speedup vs baseline: 3.6031x; 3.6031x over previous
//
#include <hip/hip_runtime.h>
#include <hip/hip_bf16.h>

#define BB 64
#define SS 512
#define TT 32
#define ENDI 31
#define NSEG 32
#define SEGLEN 16
#define HALF 8
#define ACCS 0   // float accumulator for sum_b (loss_b)
#define CNTS 1   // uint completion counter
#define GOLDB 16 // per-task gold partials, BB*NSEG slots

typedef __attribute__((ext_vector_type(8))) short s8v;    // 8 bf16 (4 VGPR)
typedef __attribute__((ext_vector_type(16))) float fx16;  // MFMA accumulator

union S8U {
  s8v v;
  unsigned int u[4];
};

__device__ __forceinline__ unsigned int cvtpk_bf16(float a, float b) {
  unsigned int r;
  asm("v_cvt_pk_bf16_f32 %0, %1, %2" : "=v"(r) : "v"(a), "v"(b));
  return r;
}

// ---------------------------------------------------------------------------
// Stage 1 (R13-proven structure + task swizzle): one BLOCK (2 waves) per
// (batch, segment). Task map: seg = blk>>6, b = (blk+seg)&63 — same-CU
// co-resident blocks (id stride 256) then step BOTH b and seg by 4, mixing
// long and short sequences per CU (read-byte balance). wave0: P_lo = E7..E0,
// wave1: P_hi = E15..E8; merge P = P_hi * P_lo via LDS + 1 matmul.
// Output: normalized 32x32 f32 matrix (max in [1,2)) + esum.
__global__ __launch_bounds__(128) void seg_kernel(
    const float* __restrict__ sc, const int* __restrict__ targets,
    const int* __restrict__ lengths, float* __restrict__ ws) {
  const int blk = blockIdx.x;
  const int seg = blk >> 6;        // [0, NSEG)
  const int b = (blk + seg) & 63;  // swizzled batch (bijective per seg)
  const int tid = threadIdx.x;
  const int wv = tid >> 6;  // 0: low half-chain, 1: high half-chain
  const int l = tid & 63;
  const int c = l & 31;
  const int h = l >> 5;
  const int len = lengths[b];
  const int lo = seg * SEGLEN;

  __shared__ alignas(16) float lm[TT * 33];  // P_hi staging, +1 pad per row
  __shared__ float meta0;                    // esum1 from wave1

  if (blk == 0 && tid == 0) {
    ws[ACCS] = 0.0f;
    ((unsigned*)ws)[CNTS] = 0u;
  }

  // ---- gold partial for s in [lo, lo+SEGLEN), wave0 only ----
  if (wv == 0) {
    float gv = 0.f;
    if (l < SEGLEN) {
      int s = lo + l;
      if (s < len) {
        int idx = b * SS + s;
        gv = sc[(size_t)idx * 1024 + (size_t)targets[idx]];
      }
    }
#pragma unroll
    for (int o = 32; o; o >>= 1) gv += __shfl_xor(gv, o);
    if (l == 0) ws[GOLDB + b * NSEG + seg] = gv;
  }

  float* mout = ws + GOLDB + BB * NSEG + (size_t)(b * NSEG + seg) * 1056;

  if (len <= lo) {  // whole segment past the sequence: identity matrix
    if (wv == 0) {
#pragma unroll
      for (int r = 0; r < 16; ++r) {
        int row = (r & 3) + 8 * (r >> 2) + 4 * h;
        mout[row * 32 + c] = (row == c) ? 1.0f : 0.0f;
      }
      if (l == 0) mout[1024] = 0.0f;
    }
    return;  // uniform per block
  }

  const int rel = len - lo;  // > 0
  // wave0 covers steps [0,8), wave1 covers [8,16)
  const int nst =
      (wv == 0)
          ? (rel < HALF ? rel : HALF)
          : (rel - HALF < 0 ? 0 : (rel - HALF < HALF ? rel - HALF : HALF));
  const float* base = sc + ((size_t)b * SS + lo + wv * HALF) * 1024;

  // B state = identity (bf16 1.0 = 0x3F80 at m == c)
  S8U B0, B1;
#pragma unroll
  for (int q = 0; q < 4; ++q) {
    B0.u[q] = 0u;
    B1.u[q] = 0u;
  }
  {
    int j0 = c - 8 * h;
    if (j0 >= 0 && j0 < 8) B0.u[j0 >> 1] |= 0x3F80u << (16 * (j0 & 1));
    int j1 = c - 16 - 8 * h;
    if (j1 >= 0 && j1 < 8) B1.u[j1 >> 1] |= 0x3F80u << (16 * (j1 & 1));
  }

#define LOADE(buf, T)                                                     \
  do {                                                                    \
    const float* _p = base + (size_t)(T) * 1024 + c * 32 + 8 * h;         \
    float4 _a = *(const float4*)_p;                                       \
    float4 _b = *(const float4*)(_p + 4);                                 \
    float4 _c = *(const float4*)(_p + 16);                                \
    float4 _d = *(const float4*)(_p + 20);                                \
    buf[0] = _a.x;  buf[1] = _a.y;  buf[2] = _a.z;  buf[3] = _a.w;        \
    buf[4] = _b.x;  buf[5] = _b.y;  buf[6] = _b.z;  buf[7] = _b.w;        \
    buf[8] = _c.x;  buf[9] = _c.y;  buf[10] = _c.z; buf[11] = _c.w;       \
    buf[12] = _d.x; buf[13] = _d.y; buf[14] = _d.z; buf[15] = _d.w;       \
  } while (0)

#define RESCALE(SVAR)                                                     \
  do {                                                                    \
    float _mx = Cl[0];                                                    \
    _Pragma("unroll") for (int q = 1; q < 16; ++q) _mx = fmaxf(_mx, Cl[q]); \
    _mx = fmaxf(_mx, __shfl_xor(_mx, 32));                                \
    _mx = fmaxf(_mx, __shfl_xor(_mx, 1));                                 \
    _mx = fmaxf(_mx, __shfl_xor(_mx, 2));                                 \
    _mx = fmaxf(_mx, __shfl_xor(_mx, 4));                                 \
    _mx = fmaxf(_mx, __shfl_xor(_mx, 8));                                 \
    _mx = fmaxf(_mx, __shfl_xor(_mx, 16));                                \
    int _ex = ((__float_as_int(_mx) >> 23) & 255) - 127;                  \
    SVAR = __int_as_float((unsigned)(127 - _ex) << 23);                   \
    esum += _ex;                                                          \
  } while (0)

#define REPACK()                                                          \
  do {                                                                    \
    unsigned int W[8], X[8];                                              \
    _Pragma("unroll") for (int q = 0; q < 8; ++q) W[q] =                  \
        cvtpk_bf16(Cl[2 * q] * s, Cl[2 * q + 1] * s);                     \
    _Pragma("unroll") for (int q = 0; q < 8; ++q) X[q] =                  \
        __shfl_xor((int)W[q], 32);                                        \
    B0.u[0] = h ? X[2] : W[0];                                            \
    B0.u[1] = h ? X[3] : W[1];                                            \
    B0.u[2] = h ? W[2] : X[0];                                            \
    B0.u[3] = h ? W[3] : X[1];                                            \
    B1.u[0] = h ? X[6] : W[4];                                            \
    B1.u[1] = h ? X[7] : W[5];                                            \
    B1.u[2] = h ? W[6] : X[4];                                            \
    B1.u[3] = h ? W[7] : X[5];                                            \
  } while (0)

  int esum = 0;
  fx16 C;
#pragma unroll
  for (int q = 0; q < 16; ++q) C[q] = 0.f;

  if (nst == HALF) {
    // ---- full 8-step half-chain: 4 phases x 2 steps, L depth 2 ----
    float L[2][16];
    S8U A2[2][2];
    LOADE(L[0], 0);
    LOADE(L[1], 1);
#pragma unroll
    for (int ph = 0; ph < 4; ++ph) {
#pragma unroll
      for (int k = 0; k < 2; ++k) {
#pragma unroll
        for (int q = 0; q < 4; ++q) {
          A2[k][0].u[q] =
              cvtpk_bf16(__expf(L[k][2 * q]), __expf(L[k][2 * q + 1]));
          A2[k][1].u[q] =
              cvtpk_bf16(__expf(L[k][8 + 2 * q]), __expf(L[k][9 + 2 * q]));
        }
      }
      if (ph < 3) {
        LOADE(L[0], ph * 2 + 2);
        LOADE(L[1], ph * 2 + 3);
      }
#pragma unroll
      for (int k = 0; k < 2; ++k) {
        const int t = ph * 2 + k;
        fx16 Cl;
#pragma unroll
        for (int q = 0; q < 16; ++q) Cl[q] = 0.f;
        Cl = __builtin_amdgcn_mfma_f32_32x32x16_bf16(A2[k][0].v, B0.v, Cl,
                                                     0, 0, 0);
        Cl = __builtin_amdgcn_mfma_f32_32x32x16_bf16(A2[k][1].v, B1.v, Cl,
                                                     0, 0, 0);
        if (t == HALF - 1) {
          C = Cl;
        } else {
          float s = 1.0f;
          if (t == 3) RESCALE(s);
          REPACK();
        }
      }
    }
  } else if (nst > 0) {
    // ---- partial half-chain: R6-proven serial loop ----
    float r0[16], r1[16], r2[16];
    LOADE(r0, 0);
    LOADE(r1, (nst > 1) ? 1 : 0);
    LOADE(r2, (nst > 2) ? 2 : 0);

#define STEPB(RB)                                                            \
    do {                                                                    \
      S8U A0, A1;                                                           \
      _Pragma("unroll") for (int q = 0; q < 4; ++q) {                       \
        A0.u[q] = cvtpk_bf16(__expf(RB[2 * q]), __expf(RB[2 * q + 1]));     \
        A1.u[q] = cvtpk_bf16(__expf(RB[8 + 2 * q]), __expf(RB[9 + 2 * q])); \
      }                                                                     \
      int _pf = t + 3;                                                      \
      if (_pf >= nst) _pf = nst - 1;                                        \
      LOADE(RB, _pf);                                                       \
      fx16 Cl;                                                              \
      _Pragma("unroll") for (int q = 0; q < 16; ++q) Cl[q] = 0.f;           \
      Cl = __builtin_amdgcn_mfma_f32_32x32x16_bf16(A0.v, B0.v, Cl, 0, 0, 0);\
      Cl = __builtin_amdgcn_mfma_f32_32x32x16_bf16(A1.v, B1.v, Cl, 0, 0, 0);\
      if (t + 1 < nst) {                                                    \
        float s = 1.0f;                                                     \
        if ((t & 3) == 3) RESCALE(s);                                       \
        REPACK();                                                           \
      } else {                                                              \
        C = Cl;                                                             \
      }                                                                     \
    } while (0)

    int t = 0;
    while (t < nst) {
      STEPB(r0);
      ++t;
      if (t >= nst) break;
      STEPB(r1);
      ++t;
      if (t >= nst) break;
      STEPB(r2);
      ++t;
    }
#undef STEPB
  }

  // ---- wave1: normalize its product and stage to LDS ----
  if (wv == 1 && nst > 0) {
    float mx = C[0];
#pragma unroll
    for (int q = 1; q < 16; ++q) mx = fmaxf(mx, C[q]);
    mx = fmaxf(mx, __shfl_xor(mx, 32));
    mx = fmaxf(mx, __shfl_xor(mx, 1));
    mx = fmaxf(mx, __shfl_xor(mx, 2));
    mx = fmaxf(mx, __shfl_xor(mx, 4));
    mx = fmaxf(mx, __shfl_xor(mx, 8));
    mx = fmaxf(mx, __shfl_xor(mx, 16));
    int ex = ((__float_as_int(mx) >> 23) & 255) - 127;
    float s1 = __int_as_float((unsigned)(127 - ex) << 23);
    esum += ex;
#pragma unroll
    for (int r = 0; r < 16; ++r) {
      int row = (r & 3) + 8 * (r >> 2) + 4 * h;
      lm[row * 33 + c] = C[r] * s1;
    }
    if (l == 0) meta0 = (float)esum;
  }
  __syncthreads();

  if (wv == 0) {
    if (rel > HALF) {
      // merge: C(P_lo) -> B via rescale+repack; A = P_hi rows from LDS
      {
        fx16 Cl = C;
        float s = 1.0f;
        RESCALE(s);
        REPACK();
      }
      S8U Am0, Am1;
#pragma unroll
      for (int q = 0; q < 4; ++q) {
        Am0.u[q] = cvtpk_bf16(lm[c * 33 + 8 * h + 2 * q],
                              lm[c * 33 + 8 * h + 2 * q + 1]);
        Am1.u[q] = cvtpk_bf16(lm[c * 33 + 16 + 8 * h + 2 * q],
                              lm[c * 33 + 16 + 8 * h + 2 * q + 1]);
      }
      fx16 Cm;
#pragma unroll
      for (int q = 0; q < 16; ++q) Cm[q] = 0.f;
      Cm = __builtin_amdgcn_mfma_f32_32x32x16_bf16(Am0.v, B0.v, Cm, 0, 0, 0);
      Cm = __builtin_amdgcn_mfma_f32_32x32x16_bf16(Am1.v, B1.v, Cm, 0, 0, 0);
      C = Cm;
      esum += (int)meta0;
    }
    // final normalize (max into [1,2)) and store f32 matrix + esum
    float mx = C[0];
#pragma unroll
    for (int q = 1; q < 16; ++q) mx = fmaxf(mx, C[q]);
    mx = fmaxf(mx, __shfl_xor(mx, 32));
    mx = fmaxf(mx, __shfl_xor(mx, 1));
    mx = fmaxf(mx, __shfl_xor(mx, 2));
    mx = fmaxf(mx, __shfl_xor(mx, 4));
    mx = fmaxf(mx, __shfl_xor(mx, 8));
    mx = fmaxf(mx, __shfl_xor(mx, 16));
    int ex = ((__float_as_int(mx) >> 23) & 255) - 127;
    float s = __int_as_float((unsigned)(127 - ex) << 23);
    esum += ex;
#pragma unroll
    for (int r = 0; r < 16; ++r) {
      int row = (r & 3) + 8 * (r >> 2) + 4 * h;
      mout[row * 32 + c] = C[r] * s;
    }
    if (l == 0) mout[1024] = (float)esum;
  }
#undef REPACK
#undef RESCALE
#undef LOADE
}

// ---------------------------------------------------------------------------
// Stage 2 (R8/R13-proven, unchanged): one block per batch, 2 waves (w = dir).
//  w0: v <- M_seg * v, seg = 0..15, v0 = ones
//  w1: r <- r * M_seg, seg = 31..16, r0 = e_END
// Power-of-2 rescale every 4th step. Block-combine:
// loss_b = (esvF+esvB)*ln2 + log(dot(vF,rB)) - gold_b, atomicAdd to ws[ACCS];
// last block (completion counter) publishes out[0].
__global__ __launch_bounds__(128) void comb_fin_kernel(
    float* __restrict__ ws, float* __restrict__ out) {
  const int b = blockIdx.x;
  const int w = threadIdx.x >> 6;
  const int l = threadIdx.x & 63;
  const int lo = l & 31;
  const int h = l >> 5;
  const int half = NSEG >> 1;
  __shared__ alignas(16) float st[2][TT];
  __shared__ float esvS[2];

#define FENCE() asm volatile("s_waitcnt lgkmcnt(0)" ::: "memory")

  float cur = w ? ((lo == ENDI) ? 1.0f : 0.0f) : 1.0f;
  st[w][lo] = cur;
  FENCE();

  const float* segbase = ws + GOLDB + BB * NSEG;
  float esv = 0.f;

#define LOADM(buf, SEG)                                                     \
  do {                                                                      \
    const float* _m = segbase + (size_t)(b * NSEG + (SEG)) * 1056;          \
    if (w == 0) {                                                           \
      const float4* _p = (const float4*)(_m + lo * 32 + h * 16);            \
      float4 _a = _p[0], _b2 = _p[1], _c2 = _p[2], _d = _p[3];              \
      buf[0] = _a.x;  buf[1] = _a.y;  buf[2] = _a.z;  buf[3] = _a.w;        \
      buf[4] = _b2.x; buf[5] = _b2.y; buf[6] = _b2.z; buf[7] = _b2.w;       \
      buf[8] = _c2.x; buf[9] = _c2.y; buf[10] = _c2.z; buf[11] = _c2.w;     \
      buf[12] = _d.x; buf[13] = _d.y; buf[14] = _d.z; buf[15] = _d.w;       \
    } else {                                                                \
      const float* _p = _m + (h * 16) * 32 + lo;                            \
      _Pragma("unroll") for (int _j = 0; _j < 16; ++_j)                     \
          buf[_j] = _p[_j * 32];                                            \
    }                                                                       \
  } while (0)

  float mc[16], mn[16];
#pragma unroll
  for (int q = 0; q < 16; ++q) mn[q] = 0.f;
  {
    int seg0 = w ? (NSEG - 1) : 0;
    LOADM(mc, seg0);
  }
  for (int k = 0; k < half; ++k) {
    int segn = w ? (NSEG - 2 - k) : (k + 1);
    if (k + 1 < half) LOADM(mn, segn);
    int segc = w ? (NSEG - 1 - k) : k;
    esv += segbase[(size_t)(b * NSEG + segc) * 1056 + 1024];
    const float4* g4 = (const float4*)st[w];
    float4 g0 = g4[h * 4 + 0], g1 = g4[h * 4 + 1], g2 = g4[h * 4 + 2],
           g3 = g4[h * 4 + 3];
    float g[16] = {g0.x, g0.y, g0.z, g0.w, g1.x, g1.y, g1.z, g1.w,
                   g2.x, g2.y, g2.z, g2.w, g3.x, g3.y, g3.z, g3.w};
    float acc[4];
#pragma unroll
    for (int q = 0; q < 4; ++q) {
      acc[q] = mc[4 * q] * g[4 * q];
#pragma unroll
      for (int t = 1; t < 4; ++t)
        acc[q] = fmaf(mc[4 * q + t], g[4 * q + t], acc[q]);
    }
    float part = (acc[0] + acc[1]) + (acc[2] + acc[3]);
    cur = part + __shfl_xor(part, 32);
    if ((k & 3) == 3) {
      float mxv = cur;
      mxv = fmaxf(mxv, __shfl_xor(mxv, 1));
      mxv = fmaxf(mxv, __shfl_xor(mxv, 2));
      mxv = fmaxf(mxv, __shfl_xor(mxv, 4));
      mxv = fmaxf(mxv, __shfl_xor(mxv, 8));
      mxv = fmaxf(mxv, __shfl_xor(mxv, 16));
      int exv = ((__float_as_int(mxv) >> 23) & 255) - 127;
      cur *= __int_as_float((unsigned)(127 - exv) << 23);
      esv += (float)exv;
    }
    FENCE();
    st[w][lo] = cur;
    FENCE();
#pragma unroll
    for (int q = 0; q < 16; ++q) mc[q] = mn[q];
  }

  if (l == 0) esvS[w] = esv;
  __syncthreads();

  if (w == 0) {
    float pr = st[0][lo] * st[1][lo];
    float gd = ws[GOLDB + b * NSEG + lo];
#pragma unroll
    for (int o = 16; o; o >>= 1) {
      pr += __shfl_xor(pr, o);
      gd += __shfl_xor(gd, o);
    }
    if (l == 0) {
      float loss =
          (esvS[0] + esvS[1]) * 0.6931471805599453f + __logf(pr) - gd;
      atomicAdd(&ws[ACCS], loss);
      __threadfence();
      unsigned old = atomicAdd(&((unsigned*)ws)[CNTS], 1u);
      if (old == BB - 1) {
        float v = atomicAdd(&ws[ACCS], 0.0f);
        out[0] = v;
      }
    }
  }
#undef LOADM
#undef FENCE
}

// ---------------------------------------------------------------------------
extern "C" void kernel_launch(void* const* d_in, const int* in_sizes, int n_in,
                              void* d_out, int out_size, void* d_ws,
                              size_t ws_size, hipStream_t stream) {
  const float* scores = (const float*)d_in[0];
  const int* targets = (const int*)d_in[1];
  const int* lengths = (const int*)d_in[2];
  float* out = (float*)d_out;
  float* ws = (float*)d_ws;

  seg_kernel<<<BB * NSEG, 128, 0, stream>>>(scores, targets, lengths, ws);
  comb_fin_kernel<<<BB, 128, 0, stream>>>(ws, out);
}